// Round 2
// baseline (1565.623 us; speedup 1.0000x reference)
//
#include <hip/hip_runtime.h>

#define D 128
#define BN_EPS 1e-5f
#define GROWS 32
#define KT 64

// ---- K1: in-degree via atomics ----
__global__ void k_deg(const int* __restrict__ dst, float* __restrict__ deg, int nE) {
    int e = blockIdx.x * 256 + threadIdx.x;
    if (e < nE) atomicAdd(&deg[dst[e]], 1.0f);
}

// ---- K2: norm = rsqrt(max(deg,1)) ----
__global__ void k_norm(const float* __restrict__ deg, float* __restrict__ norm, int nN) {
    int i = blockIdx.x * 256 + threadIdx.x;
    if (i < nN) norm[i] = rsqrtf(fmaxf(deg[i], 1.0f));
}

// ---- K3: scatter-add  agg[dst] += feat[src]*norm[src] ----
// 32 threads per edge, 4 dims (float4) per thread.
__global__ void k_scatter(const int* __restrict__ src, const int* __restrict__ dst,
                          const float* __restrict__ feat,
                          const float* __restrict__ norm,
                          float* __restrict__ agg, int nE) {
    int t = blockIdx.x * 256 + threadIdx.x;
    int e = t >> 5;
    if (e >= nE) return;
    int lane = t & 31;
    int s = src[e], d = dst[e];
    float nm = norm[s];
    const float4 f = *(const float4*)(feat + (size_t)s * D + lane * 4);
    float* ap = agg + (size_t)d * D + lane * 4;
    atomicAdd(ap + 0, f.x * nm);
    atomicAdd(ap + 1, f.y * nm);
    atomicAdd(ap + 2, f.z * nm);
    atomicAdd(ap + 3, f.w * nm);
}

// ---- K4: h = (agg @ W^T + b) * norm, in-place over agg; BN partial sums ----
// 32 rows/block, 256 threads, 4 rows x 4 cols per thread, K tiled by 64.
__global__ __launch_bounds__(256) void k_gemm(
        float* agg,                              // in: agg rows, out: h rows (in-place; = d_out)
        const float* __restrict__ W,             // (D,D) row-major fp32
        const float* __restrict__ b,             // (D,)
        const float* __restrict__ norm,
        float* __restrict__ colsum, float* __restrict__ colsq,
        int nN) {
    __shared__ float Wt[KT][132];        // Wt[kk][j] = W[j][kt+kk]   (33792 B)
    __shared__ float arow[GROWS][128];   // A rows                    (16384 B)
    __shared__ float red[256];           // BN block reduction        (1024 B)

    const int tid = threadIdx.x;
    const int row0 = blockIdx.x * GROWS;

    red[tid] = 0.0f;  // visible by the k-loop's first __syncthreads

    // Stage A rows into LDS (float4, coalesced)
    for (int idx4 = tid; idx4 < (GROWS * 128 / 4); idx4 += 256) {
        int r = idx4 >> 5;
        int k0 = (idx4 & 31) << 2;
        int gr = row0 + r;
        float4 v = {0.0f, 0.0f, 0.0f, 0.0f};
        if (gr < nN) v = *(const float4*)(agg + (size_t)gr * 128 + k0);
        *(float4*)(&arow[r][k0]) = v;
    }

    const int jg = tid & 31, rg = tid >> 5;
    const int j0 = jg << 2, r0 = rg << 2;

    float sum[4][4];
    #pragma unroll
    for (int r = 0; r < 4; r++)
        #pragma unroll
        for (int c = 0; c < 4; c++) sum[r][c] = 0.0f;

    for (int kt = 0; kt < 128; kt += KT) {
        __syncthreads();   // also covers arow staging (1st iter) / prev-tile readers
        // Stage Wt for this K-tile: W[j][kt+kk], j in [0,128), kk in [0,KT)
        for (int idx4 = tid; idx4 < (128 * KT / 4); idx4 += 256) {
            int j = idx4 >> 4;            // KT/4 = 16 chunks per W row
            int kk0 = (idx4 & 15) << 2;
            float4 w = *(const float4*)(W + (size_t)j * 128 + kt + kk0);
            Wt[kk0 + 0][j] = w.x;
            Wt[kk0 + 1][j] = w.y;
            Wt[kk0 + 2][j] = w.z;
            Wt[kk0 + 3][j] = w.w;
        }
        __syncthreads();

        for (int kk = 0; kk < KT; kk += 4) {
            float4 w0 = *(const float4*)(&Wt[kk + 0][j0]);
            float4 w1 = *(const float4*)(&Wt[kk + 1][j0]);
            float4 w2 = *(const float4*)(&Wt[kk + 2][j0]);
            float4 w3 = *(const float4*)(&Wt[kk + 3][j0]);
            #pragma unroll
            for (int r = 0; r < 4; r++) {
                float4 a = *(const float4*)(&arow[r0 + r][kt + kk]);
                sum[r][0] += a.x * w0.x + a.y * w1.x + a.z * w2.x + a.w * w3.x;
                sum[r][1] += a.x * w0.y + a.y * w1.y + a.z * w2.y + a.w * w3.y;
                sum[r][2] += a.x * w0.z + a.y * w1.z + a.z * w2.z + a.w * w3.z;
                sum[r][3] += a.x * w0.w + a.y * w1.w + a.z * w2.w + a.w * w3.w;
            }
        }
    }

    const float bj0 = b[j0], bj1 = b[j0 + 1], bj2 = b[j0 + 2], bj3 = b[j0 + 3];
    float s1[4] = {0, 0, 0, 0}, s2[4] = {0, 0, 0, 0};
    #pragma unroll
    for (int r = 0; r < 4; r++) {
        int gr = row0 + r0 + r;
        if (gr < nN) {
            float nm = norm[gr];
            float4 hv;
            hv.x = (sum[r][0] + bj0) * nm;
            hv.y = (sum[r][1] + bj1) * nm;
            hv.z = (sum[r][2] + bj2) * nm;
            hv.w = (sum[r][3] + bj3) * nm;
            *(float4*)(agg + (size_t)gr * 128 + j0) = hv;   // in-place h write
            s1[0] += hv.x; s1[1] += hv.y; s1[2] += hv.z; s1[3] += hv.w;
            s2[0] += hv.x * hv.x; s2[1] += hv.y * hv.y; s2[2] += hv.z * hv.z; s2[3] += hv.w * hv.w;
        }
    }

    #pragma unroll
    for (int c = 0; c < 4; c++) {
        atomicAdd(&red[j0 + c], s1[c]);
        atomicAdd(&red[128 + j0 + c], s2[c]);
    }
    __syncthreads();
    if (tid < 128) {
        atomicAdd(&colsum[tid], red[tid]);
        atomicAdd(&colsq[tid], red[128 + tid]);
    }
}

// ---- K5: BN parameter fold ----
__global__ void k_bnparam(const float* __restrict__ colsum, const float* __restrict__ colsq,
                          const float* __restrict__ gamma, const float* __restrict__ beta,
                          float* __restrict__ scale, float* __restrict__ shift, int nN) {
    int j = threadIdx.x;
    float inv_n = 1.0f / (float)nN;
    float mean = colsum[j] * inv_n;
    float var = colsq[j] * inv_n - mean * mean;
    float sc = gamma[j] * rsqrtf(var + BN_EPS);
    scale[j] = sc;
    shift[j] = beta[j] - mean * sc;
}

// ---- K6: out = feat + relu(h*scale + shift), in-place over h (= d_out) ----
__global__ void k_out(float* __restrict__ h, const float* __restrict__ feat,
                      const float* __restrict__ scale, const float* __restrict__ shift,
                      int total4) {
    int t = blockIdx.x * 256 + threadIdx.x;
    if (t >= total4) return;
    int base = t * 4;
    int j = base & 127;
    float4 hv = *(const float4*)(h + base);
    float4 fv = *(const float4*)(feat + base);
    float4 o;
    o.x = fv.x + fmaxf(hv.x * scale[j + 0] + shift[j + 0], 0.0f);
    o.y = fv.y + fmaxf(hv.y * scale[j + 1] + shift[j + 1], 0.0f);
    o.z = fv.z + fmaxf(hv.z * scale[j + 2] + shift[j + 2], 0.0f);
    o.w = fv.w + fmaxf(hv.w * scale[j + 3] + shift[j + 3], 0.0f);
    *(float4*)(h + base) = o;
}

extern "C" void kernel_launch(void* const* d_in, const int* in_sizes, int n_in,
                              void* d_out, int out_size, void* d_ws, size_t ws_size,
                              hipStream_t stream) {
    const float* feat  = (const float*)d_in[0];
    const float* W     = (const float*)d_in[1];
    const float* b     = (const float*)d_in[2];
    const float* gamma = (const float*)d_in[3];
    const float* beta  = (const float*)d_in[4];
    const int* esrc = (const int*)d_in[5];
    const int* edst = (const int*)d_in[6];

    const int nN = in_sizes[0] / D;
    const int nE = in_sizes[5];

    // agg/h lives in d_out (exactly nN*D fp32). Workspace: only small arrays.
    float* agg    = (float*)d_out;
    float* ws     = (float*)d_ws;
    float* deg    = ws;                 // nN
    float* norm   = deg + nN;           // nN
    float* colsum = norm + nN;          // 128
    float* colsq  = colsum + 128;       // 128
    float* scale  = colsq + 128;        // 128
    float* shift  = scale + 128;        // 128

    hipMemsetAsync(agg, 0, (size_t)nN * D * sizeof(float), stream);
    hipMemsetAsync(deg, 0, (size_t)nN * sizeof(float), stream);
    hipMemsetAsync(colsum, 0, 256 * sizeof(float), stream);

    k_deg<<<(nE + 255) / 256, 256, 0, stream>>>(edst, deg, nE);
    k_norm<<<(nN + 255) / 256, 256, 0, stream>>>(deg, norm, nN);

    long long sthreads = (long long)nE * 32;
    k_scatter<<<(int)((sthreads + 255) / 256), 256, 0, stream>>>(esrc, edst, feat, norm, agg, nE);

    k_gemm<<<(nN + GROWS - 1) / GROWS, 256, 0, stream>>>(agg, W, b, norm, colsum, colsq, nN);

    k_bnparam<<<1, 128, 0, stream>>>(colsum, colsq, gamma, beta, scale, shift, nN);

    int total4 = nN * D / 4;
    k_out<<<(total4 + 255) / 256, 256, 0, stream>>>(agg, feat, scale, shift, total4);
}

// Round 3
// 479.740 us; speedup vs baseline: 3.2635x; 3.2635x over previous
//
#include <hip/hip_runtime.h>

#define D 128
#define BN_EPS 1e-5f
#define GROWS 32
#define KT 64
#define SCAN_T 1024

// ---- K1: in-degree histogram (int atomics) ----
__global__ void k_hist(const int* __restrict__ dst, int* __restrict__ deg, int nE) {
    int e = blockIdx.x * 256 + threadIdx.x;
    if (e < nE) atomicAdd(&deg[dst[e]], 1);
}

// ---- K2: norm = rsqrt(max(deg,1)) ----
__global__ void k_norm(const int* __restrict__ deg, float* __restrict__ norm, int nN) {
    int i = blockIdx.x * 256 + threadIdx.x;
    if (i < nN) norm[i] = rsqrtf(fmaxf((float)deg[i], 1.0f));
}

// ---- K3: single-block exclusive scan over deg -> offs[nN+1], cursor copy ----
__global__ __launch_bounds__(SCAN_T) void k_scan(const int* __restrict__ deg,
                                                 int* __restrict__ offs,
                                                 int* __restrict__ cursor, int nN) {
    __shared__ int part[SCAN_T];
    const int t = threadIdx.x;
    const int chunk = (nN + SCAN_T - 1) / SCAN_T;
    const int lo = t * chunk;
    const int hi = min(lo + chunk, nN);
    int s = 0;
    for (int i = lo; i < hi; ++i) s += deg[i];
    part[t] = s;
    __syncthreads();
    // Hillis-Steele inclusive scan over 1024 partials
    for (int off = 1; off < SCAN_T; off <<= 1) {
        int v = (t >= off) ? part[t - off] : 0;
        __syncthreads();
        part[t] += v;
        __syncthreads();
    }
    int base = (t == 0) ? 0 : part[t - 1];
    for (int i = lo; i < hi; ++i) {
        offs[i] = base;
        cursor[i] = base;
        base += deg[i];
    }
    if (t == SCAN_T - 1) offs[nN] = base;   // lo >= nN for last thread => base = total
}

// ---- K4: bucket edges by dst: srcs[slot] = src ----
__global__ void k_bucket(const int* __restrict__ src, const int* __restrict__ dst,
                         int* __restrict__ cursor, int* __restrict__ srcs, int nE) {
    int e = blockIdx.x * 256 + threadIdx.x;
    if (e < nE) {
        int d = dst[e];
        int slot = atomicAdd(&cursor[d], 1);
        srcs[slot] = src[e];
    }
}

// ---- K5: gather-aggregate: agg[n][j] = sum_{s in N(n)} feat[s][j]*norm[s] ----
// 128 threads per node (1 dim each), 2 nodes per 256-thread block.
__global__ __launch_bounds__(256) void k_gather(const int* __restrict__ offs,
                                                const int* __restrict__ srcs,
                                                const float* __restrict__ feat,
                                                const float* __restrict__ norm,
                                                float* __restrict__ agg, int nN) {
    int node = blockIdx.x * 2 + (threadIdx.x >> 7);
    int j = threadIdx.x & 127;
    if (node >= nN) return;
    int i = offs[node], end = offs[node + 1];
    float acc = 0.0f;
    for (; i + 1 < end; i += 2) {
        int s0 = srcs[i], s1 = srcs[i + 1];
        float n0 = norm[s0], n1 = norm[s1];
        float f0 = feat[(size_t)s0 * D + j];
        float f1 = feat[(size_t)s1 * D + j];
        acc += f0 * n0 + f1 * n1;
    }
    if (i < end) {
        int s = srcs[i];
        acc += feat[(size_t)s * D + j] * norm[s];
    }
    agg[(size_t)node * D + j] = acc;
}

// ---- K6: h = (agg @ W^T + b) * norm, in-place over agg; BN partial sums ----
__global__ __launch_bounds__(256) void k_gemm(
        float* agg,                              // in: agg rows, out: h rows (in-place; = d_out)
        const float* __restrict__ W,             // (D,D) row-major fp32
        const float* __restrict__ b,
        const float* __restrict__ norm,
        float* __restrict__ colsum, float* __restrict__ colsq,
        int nN) {
    __shared__ float Wt[KT][132];
    __shared__ float arow[GROWS][128];
    __shared__ float red[256];

    const int tid = threadIdx.x;
    const int row0 = blockIdx.x * GROWS;

    red[tid] = 0.0f;

    for (int idx4 = tid; idx4 < (GROWS * 128 / 4); idx4 += 256) {
        int r = idx4 >> 5;
        int k0 = (idx4 & 31) << 2;
        int gr = row0 + r;
        float4 v = {0.0f, 0.0f, 0.0f, 0.0f};
        if (gr < nN) v = *(const float4*)(agg + (size_t)gr * 128 + k0);
        *(float4*)(&arow[r][k0]) = v;
    }

    const int jg = tid & 31, rg = tid >> 5;
    const int j0 = jg << 2, r0 = rg << 2;

    float sum[4][4];
    #pragma unroll
    for (int r = 0; r < 4; r++)
        #pragma unroll
        for (int c = 0; c < 4; c++) sum[r][c] = 0.0f;

    for (int kt = 0; kt < 128; kt += KT) {
        __syncthreads();
        for (int idx4 = tid; idx4 < (128 * KT / 4); idx4 += 256) {
            int j = idx4 >> 4;
            int kk0 = (idx4 & 15) << 2;
            float4 w = *(const float4*)(W + (size_t)j * 128 + kt + kk0);
            Wt[kk0 + 0][j] = w.x;
            Wt[kk0 + 1][j] = w.y;
            Wt[kk0 + 2][j] = w.z;
            Wt[kk0 + 3][j] = w.w;
        }
        __syncthreads();

        for (int kk = 0; kk < KT; kk += 4) {
            float4 w0 = *(const float4*)(&Wt[kk + 0][j0]);
            float4 w1 = *(const float4*)(&Wt[kk + 1][j0]);
            float4 w2 = *(const float4*)(&Wt[kk + 2][j0]);
            float4 w3 = *(const float4*)(&Wt[kk + 3][j0]);
            #pragma unroll
            for (int r = 0; r < 4; r++) {
                float4 a = *(const float4*)(&arow[r0 + r][kt + kk]);
                sum[r][0] += a.x * w0.x + a.y * w1.x + a.z * w2.x + a.w * w3.x;
                sum[r][1] += a.x * w0.y + a.y * w1.y + a.z * w2.y + a.w * w3.y;
                sum[r][2] += a.x * w0.z + a.y * w1.z + a.z * w2.z + a.w * w3.z;
                sum[r][3] += a.x * w0.w + a.y * w1.w + a.z * w2.w + a.w * w3.w;
            }
        }
    }

    const float bj0 = b[j0], bj1 = b[j0 + 1], bj2 = b[j0 + 2], bj3 = b[j0 + 3];
    float s1[4] = {0, 0, 0, 0}, s2[4] = {0, 0, 0, 0};
    #pragma unroll
    for (int r = 0; r < 4; r++) {
        int gr = row0 + r0 + r;
        if (gr < nN) {
            float nm = norm[gr];
            float4 hv;
            hv.x = (sum[r][0] + bj0) * nm;
            hv.y = (sum[r][1] + bj1) * nm;
            hv.z = (sum[r][2] + bj2) * nm;
            hv.w = (sum[r][3] + bj3) * nm;
            *(float4*)(agg + (size_t)gr * 128 + j0) = hv;
            s1[0] += hv.x; s1[1] += hv.y; s1[2] += hv.z; s1[3] += hv.w;
            s2[0] += hv.x * hv.x; s2[1] += hv.y * hv.y; s2[2] += hv.z * hv.z; s2[3] += hv.w * hv.w;
        }
    }

    #pragma unroll
    for (int c = 0; c < 4; c++) {
        atomicAdd(&red[j0 + c], s1[c]);
        atomicAdd(&red[128 + j0 + c], s2[c]);
    }
    __syncthreads();
    if (tid < 128) {
        atomicAdd(&colsum[tid], red[tid]);
        atomicAdd(&colsq[tid], red[128 + tid]);
    }
}

// ---- K7: BN parameter fold ----
__global__ void k_bnparam(const float* __restrict__ colsum, const float* __restrict__ colsq,
                          const float* __restrict__ gamma, const float* __restrict__ beta,
                          float* __restrict__ scale, float* __restrict__ shift, int nN) {
    int j = threadIdx.x;
    float inv_n = 1.0f / (float)nN;
    float mean = colsum[j] * inv_n;
    float var = colsq[j] * inv_n - mean * mean;
    float sc = gamma[j] * rsqrtf(var + BN_EPS);
    scale[j] = sc;
    shift[j] = beta[j] - mean * sc;
}

// ---- K8: out = feat + relu(h*scale + shift), in-place over h (= d_out) ----
__global__ void k_out(float* __restrict__ h, const float* __restrict__ feat,
                      const float* __restrict__ scale, const float* __restrict__ shift,
                      int total4) {
    int t = blockIdx.x * 256 + threadIdx.x;
    if (t >= total4) return;
    int base = t * 4;
    int j = base & 127;
    float4 hv = *(const float4*)(h + base);
    float4 fv = *(const float4*)(feat + base);
    float4 o;
    o.x = fv.x + fmaxf(hv.x * scale[j + 0] + shift[j + 0], 0.0f);
    o.y = fv.y + fmaxf(hv.y * scale[j + 1] + shift[j + 1], 0.0f);
    o.z = fv.z + fmaxf(hv.z * scale[j + 2] + shift[j + 2], 0.0f);
    o.w = fv.w + fmaxf(hv.w * scale[j + 3] + shift[j + 3], 0.0f);
    *(float4*)(h + base) = o;
}

extern "C" void kernel_launch(void* const* d_in, const int* in_sizes, int n_in,
                              void* d_out, int out_size, void* d_ws, size_t ws_size,
                              hipStream_t stream) {
    const float* feat  = (const float*)d_in[0];
    const float* W     = (const float*)d_in[1];
    const float* b     = (const float*)d_in[2];
    const float* gamma = (const float*)d_in[3];
    const float* beta  = (const float*)d_in[4];
    const int* esrc = (const int*)d_in[5];
    const int* edst = (const int*)d_in[6];

    const int nN = in_sizes[0] / D;
    const int nE = in_sizes[5];

    float* agg = (float*)d_out;          // nN*D fp32, in-place h, then out

    // workspace layout (ints then floats)
    int*   deg    = (int*)d_ws;          // nN
    int*   offs   = deg + nN;            // nN+1
    int*   cursor = offs + nN + 1;       // nN
    int*   srcs   = cursor + nN;         // nE
    float* norm   = (float*)(srcs + nE); // nN
    float* colsum = norm + nN;           // 128
    float* colsq  = colsum + 128;        // 128
    float* scale  = colsq + 128;         // 128
    float* shift  = scale + 128;         // 128

    hipMemsetAsync(deg, 0, (size_t)nN * sizeof(int), stream);
    hipMemsetAsync(colsum, 0, 256 * sizeof(float), stream);

    k_hist<<<(nE + 255) / 256, 256, 0, stream>>>(edst, deg, nE);
    k_norm<<<(nN + 255) / 256, 256, 0, stream>>>(deg, norm, nN);
    k_scan<<<1, SCAN_T, 0, stream>>>(deg, offs, cursor, nN);
    k_bucket<<<(nE + 255) / 256, 256, 0, stream>>>(esrc, edst, cursor, srcs, nE);
    k_gather<<<(nN + 1) / 2, 256, 0, stream>>>(offs, srcs, feat, norm, agg, nN);
    k_gemm<<<(nN + GROWS - 1) / GROWS, 256, 0, stream>>>(agg, W, b, norm, colsum, colsq, nN);
    k_bnparam<<<1, 128, 0, stream>>>(colsum, colsq, gamma, beta, scale, shift, nN);

    int total4 = nN * D / 4;
    k_out<<<(total4 + 255) / 256, 256, 0, stream>>>(agg, feat, scale, shift, total4);
}

// Round 4
// 368.599 us; speedup vs baseline: 4.2475x; 1.3015x over previous
//
#include <hip/hip_runtime.h>

#define D 128
#define BN_EPS 1e-5f
#define GROWS 32
#define KT 64

// ---- K1: in-degree histogram (int atomics) ----
__global__ void k_hist(const int* __restrict__ dst, int* __restrict__ deg, int nE) {
    int e = blockIdx.x * 256 + threadIdx.x;
    if (e < nE) atomicAdd(&deg[dst[e]], 1);
}

// ---- K2: claim CSR slot ranges (unordered) + norm ----
// Wave-level inclusive scan of deg, one global atomic per wave.
__global__ __launch_bounds__(256) void k_claim(const int* __restrict__ deg,
                                               int* __restrict__ offs,
                                               int* __restrict__ cursor,
                                               float* __restrict__ norm,
                                               int* __restrict__ counter, int nN) {
    int i = blockIdx.x * 256 + threadIdx.x;
    int lane = threadIdx.x & 63;
    int d = (i < nN) ? deg[i] : 0;
    int x = d;                                   // inclusive scan over the wave
    #pragma unroll
    for (int off = 1; off < 64; off <<= 1) {
        int v = __shfl_up(x, off, 64);
        if (lane >= off) x += v;
    }
    int total = __shfl(x, 63, 64);
    int base = 0;
    if (lane == 63 && total > 0) base = atomicAdd(counter, total);
    base = __shfl(base, 63, 64);
    if (i < nN) {
        int o = base + x - d;
        offs[i] = o;
        cursor[i] = o;
        norm[i] = rsqrtf(fmaxf((float)d, 1.0f));
    }
}

// ---- K3: bucket edges by dst: srcs[slot] = src ----
__global__ void k_bucket(const int* __restrict__ src, const int* __restrict__ dst,
                         int* __restrict__ cursor, int* __restrict__ srcs, int nE) {
    int e = blockIdx.x * 256 + threadIdx.x;
    if (e < nE) {
        int d = dst[e];
        int slot = atomicAdd(&cursor[d], 1);
        srcs[slot] = src[e];
    }
}

// ---- K4: gather-aggregate: agg[n][j] = sum_{s in N(n)} feat[s][j]*norm[s] ----
// 128 threads per node (1 dim each), 2 nodes per 256-thread block.
__global__ __launch_bounds__(256) void k_gather(const int* __restrict__ offs,
                                                const int* __restrict__ deg,
                                                const int* __restrict__ srcs,
                                                const float* __restrict__ feat,
                                                const float* __restrict__ norm,
                                                float* __restrict__ agg, int nN) {
    int node = blockIdx.x * 2 + (threadIdx.x >> 7);
    int j = threadIdx.x & 127;
    if (node >= nN) return;
    int i = offs[node];
    int end = i + deg[node];
    float acc = 0.0f;
    for (; i + 1 < end; i += 2) {
        int s0 = srcs[i], s1 = srcs[i + 1];
        float n0 = norm[s0], n1 = norm[s1];
        float f0 = feat[(size_t)s0 * D + j];
        float f1 = feat[(size_t)s1 * D + j];
        acc += f0 * n0 + f1 * n1;
    }
    if (i < end) {
        int s = srcs[i];
        acc += feat[(size_t)s * D + j] * norm[s];
    }
    agg[(size_t)node * D + j] = acc;
}

// ---- K5: h = (agg @ W^T + b) * norm, in-place over agg; BN partial sums ----
__global__ __launch_bounds__(256) void k_gemm(
        float* agg,                              // in: agg rows, out: h rows (in-place; = d_out)
        const float* __restrict__ W,             // (D,D) row-major fp32
        const float* __restrict__ b,
        const float* __restrict__ norm,
        float* __restrict__ colsum, float* __restrict__ colsq,
        int nN) {
    __shared__ float Wt[KT][132];
    __shared__ float arow[GROWS][128];
    __shared__ float red[256];

    const int tid = threadIdx.x;
    const int row0 = blockIdx.x * GROWS;

    red[tid] = 0.0f;

    for (int idx4 = tid; idx4 < (GROWS * 128 / 4); idx4 += 256) {
        int r = idx4 >> 5;
        int k0 = (idx4 & 31) << 2;
        int gr = row0 + r;
        float4 v = {0.0f, 0.0f, 0.0f, 0.0f};
        if (gr < nN) v = *(const float4*)(agg + (size_t)gr * 128 + k0);
        *(float4*)(&arow[r][k0]) = v;
    }

    const int jg = tid & 31, rg = tid >> 5;
    const int j0 = jg << 2, r0 = rg << 2;

    float sum[4][4];
    #pragma unroll
    for (int r = 0; r < 4; r++)
        #pragma unroll
        for (int c = 0; c < 4; c++) sum[r][c] = 0.0f;

    for (int kt = 0; kt < 128; kt += KT) {
        __syncthreads();
        for (int idx4 = tid; idx4 < (128 * KT / 4); idx4 += 256) {
            int j = idx4 >> 4;
            int kk0 = (idx4 & 15) << 2;
            float4 w = *(const float4*)(W + (size_t)j * 128 + kt + kk0);
            Wt[kk0 + 0][j] = w.x;
            Wt[kk0 + 1][j] = w.y;
            Wt[kk0 + 2][j] = w.z;
            Wt[kk0 + 3][j] = w.w;
        }
        __syncthreads();

        for (int kk = 0; kk < KT; kk += 4) {
            float4 w0 = *(const float4*)(&Wt[kk + 0][j0]);
            float4 w1 = *(const float4*)(&Wt[kk + 1][j0]);
            float4 w2 = *(const float4*)(&Wt[kk + 2][j0]);
            float4 w3 = *(const float4*)(&Wt[kk + 3][j0]);
            #pragma unroll
            for (int r = 0; r < 4; r++) {
                float4 a = *(const float4*)(&arow[r0 + r][kt + kk]);
                sum[r][0] += a.x * w0.x + a.y * w1.x + a.z * w2.x + a.w * w3.x;
                sum[r][1] += a.x * w0.y + a.y * w1.y + a.z * w2.y + a.w * w3.y;
                sum[r][2] += a.x * w0.z + a.y * w1.z + a.z * w2.z + a.w * w3.z;
                sum[r][3] += a.x * w0.w + a.y * w1.w + a.z * w2.w + a.w * w3.w;
            }
        }
    }

    const float bj0 = b[j0], bj1 = b[j0 + 1], bj2 = b[j0 + 2], bj3 = b[j0 + 3];
    float s1[4] = {0, 0, 0, 0}, s2[4] = {0, 0, 0, 0};
    #pragma unroll
    for (int r = 0; r < 4; r++) {
        int gr = row0 + r0 + r;
        if (gr < nN) {
            float nm = norm[gr];
            float4 hv;
            hv.x = (sum[r][0] + bj0) * nm;
            hv.y = (sum[r][1] + bj1) * nm;
            hv.z = (sum[r][2] + bj2) * nm;
            hv.w = (sum[r][3] + bj3) * nm;
            *(float4*)(agg + (size_t)gr * 128 + j0) = hv;
            s1[0] += hv.x; s1[1] += hv.y; s1[2] += hv.z; s1[3] += hv.w;
            s2[0] += hv.x * hv.x; s2[1] += hv.y * hv.y; s2[2] += hv.z * hv.z; s2[3] += hv.w * hv.w;
        }
    }

    #pragma unroll
    for (int c = 0; c < 4; c++) {
        atomicAdd(&red[j0 + c], s1[c]);
        atomicAdd(&red[128 + j0 + c], s2[c]);
    }
    __syncthreads();
    if (tid < 128) {
        atomicAdd(&colsum[tid], red[tid]);
        atomicAdd(&colsq[tid], red[128 + tid]);
    }
}

// ---- K6: BN parameter fold ----
__global__ void k_bnparam(const float* __restrict__ colsum, const float* __restrict__ colsq,
                          const float* __restrict__ gamma, const float* __restrict__ beta,
                          float* __restrict__ scale, float* __restrict__ shift, int nN) {
    int j = threadIdx.x;
    float inv_n = 1.0f / (float)nN;
    float mean = colsum[j] * inv_n;
    float var = colsq[j] * inv_n - mean * mean;
    float sc = gamma[j] * rsqrtf(var + BN_EPS);
    scale[j] = sc;
    shift[j] = beta[j] - mean * sc;
}

// ---- K7: out = feat + relu(h*scale + shift), in-place over h (= d_out) ----
__global__ void k_out(float* __restrict__ h, const float* __restrict__ feat,
                      const float* __restrict__ scale, const float* __restrict__ shift,
                      int total4) {
    int t = blockIdx.x * 256 + threadIdx.x;
    if (t >= total4) return;
    int base = t * 4;
    int j = base & 127;
    float4 hv = *(const float4*)(h + base);
    float4 fv = *(const float4*)(feat + base);
    float4 o;
    o.x = fv.x + fmaxf(hv.x * scale[j + 0] + shift[j + 0], 0.0f);
    o.y = fv.y + fmaxf(hv.y * scale[j + 1] + shift[j + 1], 0.0f);
    o.z = fv.z + fmaxf(hv.z * scale[j + 2] + shift[j + 2], 0.0f);
    o.w = fv.w + fmaxf(hv.w * scale[j + 3] + shift[j + 3], 0.0f);
    *(float4*)(h + base) = o;
}

extern "C" void kernel_launch(void* const* d_in, const int* in_sizes, int n_in,
                              void* d_out, int out_size, void* d_ws, size_t ws_size,
                              hipStream_t stream) {
    const float* feat  = (const float*)d_in[0];
    const float* W     = (const float*)d_in[1];
    const float* b     = (const float*)d_in[2];
    const float* gamma = (const float*)d_in[3];
    const float* beta  = (const float*)d_in[4];
    const int* esrc = (const int*)d_in[5];
    const int* edst = (const int*)d_in[6];

    const int nN = in_sizes[0] / D;
    const int nE = in_sizes[5];

    float* agg = (float*)d_out;          // nN*D fp32, in-place h, then out

    // workspace layout (ints then floats)
    int*   deg     = (int*)d_ws;          // nN
    int*   offs    = deg + nN;            // nN
    int*   cursor  = offs + nN;           // nN
    int*   srcs    = cursor + nN;         // nE
    float* norm    = (float*)(srcs + nE); // nN
    float* colsum  = norm + nN;           // 128
    float* colsq   = colsum + 128;        // 128
    float* scale   = colsq + 128;         // 128
    float* shift   = scale + 128;         // 128
    int*   counter = (int*)(shift + 128); // 1

    hipMemsetAsync(deg, 0, (size_t)nN * sizeof(int), stream);
    // zero colsum, colsq (scale/shift are overwritten) and counter
    hipMemsetAsync(colsum, 0, (4 * 128 + 1) * sizeof(float), stream);

    k_hist<<<(nE + 255) / 256, 256, 0, stream>>>(edst, deg, nE);
    k_claim<<<(nN + 255) / 256, 256, 0, stream>>>(deg, offs, cursor, norm, counter, nN);
    k_bucket<<<(nE + 255) / 256, 256, 0, stream>>>(esrc, edst, cursor, srcs, nE);
    k_gather<<<(nN + 1) / 2, 256, 0, stream>>>(offs, deg, srcs, feat, norm, agg, nN);
    k_gemm<<<(nN + GROWS - 1) / GROWS, 256, 0, stream>>>(agg, W, b, norm, colsum, colsq, nN);
    k_bnparam<<<1, 128, 0, stream>>>(colsum, colsq, gamma, beta, scale, shift, nN);

    int total4 = nN * D / 4;
    k_out<<<(total4 + 255) / 256, 256, 0, stream>>>(agg, feat, scale, shift, total4);
}

// Round 5
// 324.998 us; speedup vs baseline: 4.8173x; 1.1342x over previous
//
#include <hip/hip_runtime.h>

#define D 128
#define BN_EPS 1e-5f
#define GROWS 32
#define KT 64

// ---- K1: in-degree histogram (int atomics) ----
__global__ void k_hist(const int* __restrict__ dst, int* __restrict__ deg, int nE) {
    int e = blockIdx.x * 256 + threadIdx.x;
    if (e < nE) atomicAdd(&deg[dst[e]], 1);
}

// ---- K2: claim CSR slot ranges (unordered) + norm ----
// Wave-level inclusive scan of deg, one global atomic per wave.
__global__ __launch_bounds__(256) void k_claim(const int* __restrict__ deg,
                                               int* __restrict__ offs,
                                               int* __restrict__ cursor,
                                               float* __restrict__ norm,
                                               int* __restrict__ counter, int nN) {
    int i = blockIdx.x * 256 + threadIdx.x;
    int lane = threadIdx.x & 63;
    int d = (i < nN) ? deg[i] : 0;
    int x = d;                                   // inclusive scan over the wave
    #pragma unroll
    for (int off = 1; off < 64; off <<= 1) {
        int v = __shfl_up(x, off, 64);
        if (lane >= off) x += v;
    }
    int total = __shfl(x, 63, 64);
    int base = 0;
    if (lane == 63 && total > 0) base = atomicAdd(counter, total);
    base = __shfl(base, 63, 64);
    if (i < nN) {
        int o = base + x - d;
        offs[i] = o;
        cursor[i] = o;
        norm[i] = rsqrtf(fmaxf((float)d, 1.0f));
    }
}

// ---- K3: bucket edges by dst: srcs[slot] = src ----
__global__ void k_bucket(const int* __restrict__ src, const int* __restrict__ dst,
                         int* __restrict__ cursor, int* __restrict__ srcs, int nE) {
    int e = blockIdx.x * 256 + threadIdx.x;
    if (e < nE) {
        int d = dst[e];
        int slot = atomicAdd(&cursor[d], 1);
        srcs[slot] = src[e];
    }
}

// ---- K4: gather-aggregate: agg[n][j] = sum_{s in N(n)} feat[s][j]*norm[s] ----
// One node per 64-lane wave; each lane owns 2 dims (float2). 4 nodes / 256-block.
__global__ __launch_bounds__(256) void k_gather(const int* __restrict__ offs,
                                                const int* __restrict__ deg,
                                                const int* __restrict__ srcs,
                                                const float* __restrict__ feat,
                                                const float* __restrict__ norm,
                                                float* __restrict__ agg, int nN) {
    int node = (blockIdx.x * 256 + threadIdx.x) >> 6;
    if (node >= nN) return;
    int lane = threadIdx.x & 63;
    const float* fbase = feat + 2 * lane;

    int i = offs[node];
    int end = i + deg[node];
    float ax = 0.0f, ay = 0.0f;

    for (; i + 3 < end; i += 4) {
        int s0 = srcs[i], s1 = srcs[i + 1], s2 = srcs[i + 2], s3 = srcs[i + 3];
        float n0 = norm[s0], n1 = norm[s1], n2 = norm[s2], n3 = norm[s3];
        float2 f0 = *(const float2*)(fbase + (size_t)s0 * D);
        float2 f1 = *(const float2*)(fbase + (size_t)s1 * D);
        float2 f2 = *(const float2*)(fbase + (size_t)s2 * D);
        float2 f3 = *(const float2*)(fbase + (size_t)s3 * D);
        ax += f0.x * n0 + f1.x * n1 + f2.x * n2 + f3.x * n3;
        ay += f0.y * n0 + f1.y * n1 + f2.y * n2 + f3.y * n3;
    }
    for (; i < end; ++i) {
        int s = srcs[i];
        float n = norm[s];
        float2 f = *(const float2*)(fbase + (size_t)s * D);
        ax += f.x * n;
        ay += f.y * n;
    }
    float2 o = {ax, ay};
    *(float2*)(agg + (size_t)node * D + 2 * lane) = o;
}

// ---- K5: h = (agg @ W^T + b) * norm, in-place over agg; BN partial sums ----
__global__ __launch_bounds__(256) void k_gemm(
        float* agg,                              // in: agg rows, out: h rows (in-place; = d_out)
        const float* __restrict__ W,             // (D,D) row-major fp32
        const float* __restrict__ b,
        const float* __restrict__ norm,
        float* __restrict__ colsum, float* __restrict__ colsq,
        int nN) {
    __shared__ float Wt[KT][132];
    __shared__ float arow[GROWS][128];
    __shared__ float red[256];

    const int tid = threadIdx.x;
    const int row0 = blockIdx.x * GROWS;

    red[tid] = 0.0f;

    for (int idx4 = tid; idx4 < (GROWS * 128 / 4); idx4 += 256) {
        int r = idx4 >> 5;
        int k0 = (idx4 & 31) << 2;
        int gr = row0 + r;
        float4 v = {0.0f, 0.0f, 0.0f, 0.0f};
        if (gr < nN) v = *(const float4*)(agg + (size_t)gr * 128 + k0);
        *(float4*)(&arow[r][k0]) = v;
    }

    const int jg = tid & 31, rg = tid >> 5;
    const int j0 = jg << 2, r0 = rg << 2;

    float sum[4][4];
    #pragma unroll
    for (int r = 0; r < 4; r++)
        #pragma unroll
        for (int c = 0; c < 4; c++) sum[r][c] = 0.0f;

    for (int kt = 0; kt < 128; kt += KT) {
        __syncthreads();
        for (int idx4 = tid; idx4 < (128 * KT / 4); idx4 += 256) {
            int j = idx4 >> 4;
            int kk0 = (idx4 & 15) << 2;
            float4 w = *(const float4*)(W + (size_t)j * 128 + kt + kk0);
            Wt[kk0 + 0][j] = w.x;
            Wt[kk0 + 1][j] = w.y;
            Wt[kk0 + 2][j] = w.z;
            Wt[kk0 + 3][j] = w.w;
        }
        __syncthreads();

        for (int kk = 0; kk < KT; kk += 4) {
            float4 w0 = *(const float4*)(&Wt[kk + 0][j0]);
            float4 w1 = *(const float4*)(&Wt[kk + 1][j0]);
            float4 w2 = *(const float4*)(&Wt[kk + 2][j0]);
            float4 w3 = *(const float4*)(&Wt[kk + 3][j0]);
            #pragma unroll
            for (int r = 0; r < 4; r++) {
                float4 a = *(const float4*)(&arow[r0 + r][kt + kk]);
                sum[r][0] += a.x * w0.x + a.y * w1.x + a.z * w2.x + a.w * w3.x;
                sum[r][1] += a.x * w0.y + a.y * w1.y + a.z * w2.y + a.w * w3.y;
                sum[r][2] += a.x * w0.z + a.y * w1.z + a.z * w2.z + a.w * w3.z;
                sum[r][3] += a.x * w0.w + a.y * w1.w + a.z * w2.w + a.w * w3.w;
            }
        }
    }

    const float bj0 = b[j0], bj1 = b[j0 + 1], bj2 = b[j0 + 2], bj3 = b[j0 + 3];
    float s1[4] = {0, 0, 0, 0}, s2[4] = {0, 0, 0, 0};
    #pragma unroll
    for (int r = 0; r < 4; r++) {
        int gr = row0 + r0 + r;
        if (gr < nN) {
            float nm = norm[gr];
            float4 hv;
            hv.x = (sum[r][0] + bj0) * nm;
            hv.y = (sum[r][1] + bj1) * nm;
            hv.z = (sum[r][2] + bj2) * nm;
            hv.w = (sum[r][3] + bj3) * nm;
            *(float4*)(agg + (size_t)gr * 128 + j0) = hv;
            s1[0] += hv.x; s1[1] += hv.y; s1[2] += hv.z; s1[3] += hv.w;
            s2[0] += hv.x * hv.x; s2[1] += hv.y * hv.y; s2[2] += hv.z * hv.z; s2[3] += hv.w * hv.w;
        }
    }

    #pragma unroll
    for (int c = 0; c < 4; c++) {
        atomicAdd(&red[j0 + c], s1[c]);
        atomicAdd(&red[128 + j0 + c], s2[c]);
    }
    __syncthreads();
    if (tid < 128) {
        atomicAdd(&colsum[tid], red[tid]);
        atomicAdd(&colsq[tid], red[128 + tid]);
    }
}

// ---- K6: BN parameter fold ----
__global__ void k_bnparam(const float* __restrict__ colsum, const float* __restrict__ colsq,
                          const float* __restrict__ gamma, const float* __restrict__ beta,
                          float* __restrict__ scale, float* __restrict__ shift, int nN) {
    int j = threadIdx.x;
    float inv_n = 1.0f / (float)nN;
    float mean = colsum[j] * inv_n;
    float var = colsq[j] * inv_n - mean * mean;
    float sc = gamma[j] * rsqrtf(var + BN_EPS);
    scale[j] = sc;
    shift[j] = beta[j] - mean * sc;
}

// ---- K7: out = feat + relu(h*scale + shift), in-place over h (= d_out) ----
__global__ void k_out(float* __restrict__ h, const float* __restrict__ feat,
                      const float* __restrict__ scale, const float* __restrict__ shift,
                      int total4) {
    int t = blockIdx.x * 256 + threadIdx.x;
    if (t >= total4) return;
    int base = t * 4;
    int j = base & 127;
    float4 hv = *(const float4*)(h + base);
    float4 fv = *(const float4*)(feat + base);
    float4 o;
    o.x = fv.x + fmaxf(hv.x * scale[j + 0] + shift[j + 0], 0.0f);
    o.y = fv.y + fmaxf(hv.y * scale[j + 1] + shift[j + 1], 0.0f);
    o.z = fv.z + fmaxf(hv.z * scale[j + 2] + shift[j + 2], 0.0f);
    o.w = fv.w + fmaxf(hv.w * scale[j + 3] + shift[j + 3], 0.0f);
    *(float4*)(h + base) = o;
}

extern "C" void kernel_launch(void* const* d_in, const int* in_sizes, int n_in,
                              void* d_out, int out_size, void* d_ws, size_t ws_size,
                              hipStream_t stream) {
    const float* feat  = (const float*)d_in[0];
    const float* W     = (const float*)d_in[1];
    const float* b     = (const float*)d_in[2];
    const float* gamma = (const float*)d_in[3];
    const float* beta  = (const float*)d_in[4];
    const int* esrc = (const int*)d_in[5];
    const int* edst = (const int*)d_in[6];

    const int nN = in_sizes[0] / D;
    const int nE = in_sizes[5];

    float* agg = (float*)d_out;          // nN*D fp32, in-place h, then out

    // workspace layout (ints then floats)
    int*   deg     = (int*)d_ws;          // nN
    int*   offs    = deg + nN;            // nN
    int*   cursor  = offs + nN;           // nN
    int*   srcs    = cursor + nN;         // nE
    float* norm    = (float*)(srcs + nE); // nN
    float* colsum  = norm + nN;           // 128
    float* colsq   = colsum + 128;        // 128
    float* scale   = colsq + 128;         // 128
    float* shift   = scale + 128;         // 128
    int*   counter = (int*)(shift + 128); // 1

    hipMemsetAsync(deg, 0, (size_t)nN * sizeof(int), stream);
    // zero colsum, colsq (scale/shift are overwritten) and counter
    hipMemsetAsync(colsum, 0, (4 * 128 + 1) * sizeof(float), stream);

    k_hist<<<(nE + 255) / 256, 256, 0, stream>>>(edst, deg, nE);
    k_claim<<<(nN + 255) / 256, 256, 0, stream>>>(deg, offs, cursor, norm, counter, nN);
    k_bucket<<<(nE + 255) / 256, 256, 0, stream>>>(esrc, edst, cursor, srcs, nE);

    int gblocks = (nN * 64 + 255) / 256;
    k_gather<<<gblocks, 256, 0, stream>>>(offs, deg, srcs, feat, norm, agg, nN);

    k_gemm<<<(nN + GROWS - 1) / GROWS, 256, 0, stream>>>(agg, W, b, norm, colsum, colsq, nN);
    k_bnparam<<<1, 128, 0, stream>>>(colsum, colsq, gamma, beta, scale, shift, nN);

    int total4 = nN * D / 4;
    k_out<<<(total4 + 255) / 256, 256, 0, stream>>>(agg, feat, scale, shift, total4);
}